// Round 4
// baseline (1597.782 us; speedup 1.0000x reference)
//
#include <hip/hip_runtime.h>
#include <math.h>

#define N_NODES   100000
#define N_EDGES   1600000
#define ETOT      1700000   // edges + self loops
#define F_IN      100
#define HEADS     3
#define HEAD_DIM  64
#define HIDDEN    192
#define NUM_GRAPHS 128
#define NUM_CLASSES 2

typedef unsigned short ushort_t;

// ---- ordered-uint encoding for float atomicMax (handles negatives) ----
__device__ __forceinline__ unsigned f2ord(float f) {
    unsigned u = __float_as_uint(f);
    return (u & 0x80000000u) ? ~u : (u | 0x80000000u);
}
__device__ __forceinline__ float ord2f(unsigned u) {
    return __uint_as_float((u & 0x80000000u) ? (u & 0x7fffffffu) : ~u);
}
__device__ __forceinline__ unsigned bf16rn(float f) {   // RTNE f32 -> bf16 bits
    unsigned u = __float_as_uint(f);
    return (u + 0x7fffu + ((u >> 16) & 1u)) >> 16;
}

// ---- K1: h = x@W, output bf16. lane=node (64/block), wave=48 features. ----
__global__ __launch_bounds__(256) void k_gemm(
        const float* __restrict__ x, const float* __restrict__ W,
        ushort_t* __restrict__ hb) {
    __shared__ float xs[64 * 101];
    const int tid = threadIdx.x;
    const int lane = tid & 63;
    const int base = blockIdx.x * 64;

    for (int idx = tid; idx < 64 * F_IN; idx += 256) {
        int g = base * F_IN + idx;
        float v = (g < N_NODES * F_IN) ? x[g] : 0.f;
        xs[(idx / F_IN) * 101 + (idx % F_IN)] = v;
    }
    __syncthreads();

    const int f0 = 48 * __builtin_amdgcn_readfirstlane(tid >> 6);

    float acc[48];
#pragma unroll
    for (int i = 0; i < 48; i++) acc[i] = 0.f;

#pragma unroll 2
    for (int k = 0; k < F_IN; k++) {
        float xk = xs[lane * 101 + k];
        const float4* wrow = (const float4*)(W + k * HIDDEN + f0);
#pragma unroll
        for (int fi = 0; fi < 12; fi++) {
            float4 w = wrow[fi];
            acc[fi * 4 + 0] += xk * w.x;
            acc[fi * 4 + 1] += xk * w.y;
            acc[fi * 4 + 2] += xk * w.z;
            acc[fi * 4 + 3] += xk * w.w;
        }
    }

    const int node = base + lane;
    if (node < N_NODES) {
        uint4* hp = (uint4*)(hb + node * HIDDEN + f0);
#pragma unroll
        for (int g = 0; g < 6; g++) {
            uint4 u;
            u.x = bf16rn(acc[g * 8 + 0]) | (bf16rn(acc[g * 8 + 1]) << 16);
            u.y = bf16rn(acc[g * 8 + 2]) | (bf16rn(acc[g * 8 + 3]) << 16);
            u.z = bf16rn(acc[g * 8 + 4]) | (bf16rn(acc[g * 8 + 5]) << 16);
            u.w = bf16rn(acc[g * 8 + 6]) | (bf16rn(acc[g * 8 + 7]) << 16);
            hp[g] = u;
        }
    }
}

// ---- K1b: wsv[k][j] = sum_c W[k][(j%3)*64+c] * att_{src|dst}[j%3][c] ----
// block = one k (100 blocks), lane-parallel dot + butterfly reduce
__global__ __launch_bounds__(64) void k_attprep(
        const float* __restrict__ W, const float* __restrict__ att_src,
        const float* __restrict__ att_dst, float* __restrict__ wsv) {
    const int k = blockIdx.x;
    const int lane = threadIdx.x;
    float w0 = W[k * HIDDEN + lane];
    float w1 = W[k * HIDDEN + 64 + lane];
    float w2 = W[k * HIDDEN + 128 + lane];
    float p[6];
    p[0] = w0 * att_src[lane];       p[1] = w1 * att_src[64 + lane];
    p[2] = w2 * att_src[128 + lane]; p[3] = w0 * att_dst[lane];
    p[4] = w1 * att_dst[64 + lane];  p[5] = w2 * att_dst[128 + lane];
#pragma unroll
    for (int j = 0; j < 6; j++)
#pragma unroll
        for (int m = 1; m < 64; m <<= 1) p[j] += __shfl_xor(p[j], m);
    if (lane == 0) {
#pragma unroll
        for (int j = 0; j < 6; j++) wsv[k * 6 + j] = p[j];
    }
}

// ---- K1c: asrc/adst = x @ wsv  (wave per node, coalesced x reads) ----
__global__ __launch_bounds__(256) void k_att(
        const float* __restrict__ x, const float* __restrict__ wsv,
        float* __restrict__ asrc, float* __restrict__ adst) {
    const int lane = threadIdx.x & 63;
    const int nid = blockIdx.x * 4 + (threadIdx.x >> 6);
    float xv0 = x[nid * F_IN + lane];
    int l2 = (lane < F_IN - 64) ? (64 + lane) : 0;
    float xv1 = (lane < F_IN - 64) ? x[nid * F_IN + 64 + lane] : 0.f;
    float p[6];
#pragma unroll
    for (int j = 0; j < 6; j++)
        p[j] = xv0 * wsv[lane * 6 + j] + xv1 * wsv[l2 * 6 + j];
#pragma unroll
    for (int j = 0; j < 6; j++)
#pragma unroll
        for (int msk = 1; msk < 64; msk <<= 1)
            p[j] += __shfl_xor(p[j], msk);
    if (lane < 3) {
        asrc[nid * HEADS + lane] = p[lane];
        adst[nid * HEADS + lane] = p[3 + lane];
    }
}

// ---- K2: histogram of incoming-edge counts per dst ----
__global__ void k_hist(const int* __restrict__ ei, int* __restrict__ count) {
    int i = blockIdx.x * blockDim.x + threadIdx.x;
    if (i >= ETOT) return;
    int d = (i < N_EDGES) ? ei[N_EDGES + i] : (i - N_EDGES);
    atomicAdd(&count[d], 1);
}

// ---- K3: exclusive scan, wave-parallel two-phase (single block) ----
__global__ __launch_bounds__(1024) void k_scan(
        const int* __restrict__ count, int* __restrict__ offs, int* __restrict__ cursor) {
    __shared__ int wsum[16];
    __shared__ int wexc[16];
    const int t = threadIdx.x, w = t >> 6, lane = t & 63;
    const int CH = N_NODES / 16;            // 6250, exact
    const int begin = w * CH, end = begin + CH;

    int s = 0;
    for (int i = begin + lane; i < end; i += 64) s += count[i];
#pragma unroll
    for (int off = 32; off; off >>= 1) s += __shfl_down(s, off);
    if (lane == 0) wsum[w] = s;
    __syncthreads();
    if (t == 0) {
        int run = 0;
        for (int i = 0; i < 16; i++) { wexc[i] = run; run += wsum[i]; }
        offs[N_NODES] = run;
    }
    __syncthreads();

    int running = wexc[w];
    for (int cb = begin; cb < end; cb += 64) {
        int i = cb + lane;
        int v = (i < end) ? count[i] : 0;
        int sc = v;
#pragma unroll
        for (int off = 1; off < 64; off <<= 1) {
            int u = __shfl_up(sc, off);
            if (lane >= off) sc += u;
        }
        if (i < end) { int e = running + sc - v; offs[i] = e; cursor[i] = e; }
        running += __shfl(sc, 63);
    }
}

// ---- K4: scatter into dst-sorted AoS {src_byte_off, exp(e0), exp(e1), exp(e2)} ----
__global__ void k_scatter(const int* __restrict__ ei,
        const float* __restrict__ asrc, const float* __restrict__ adst,
        int* __restrict__ cursor, uint4* __restrict__ aos) {
    int i = blockIdx.x * blockDim.x + threadIdx.x;
    if (i >= ETOT) return;
    int s, d;
    if (i < N_EDGES) { s = ei[i]; d = ei[N_EDGES + i]; }
    else             { s = d = i - N_EDGES; }
    int pos = atomicAdd(&cursor[d], 1);
    float e[HEADS];
#pragma unroll
    for (int hh = 0; hh < HEADS; hh++) {
        float v = asrc[s * HEADS + hh] + adst[d * HEADS + hh];
        v = (v > 0.f) ? v : 0.2f * v;       // leaky_relu slope 0.2
        e[hh] = expf(v);                    // max-free softmax numerator
    }
    uint4 rec;
    rec.x = (unsigned)(s * (HIDDEN * 2));   // byte offset of bf16 row
    rec.y = __float_as_uint(e[0]);
    rec.z = __float_as_uint(e[1]);
    rec.w = __float_as_uint(e[2]);
    aos[pos] = rec;
}

// ---- K5: softmax-aggregate + bias + leaky_relu + pool(max) ----
// wave = (node, head). 8 lanes per edge-row: lane loads uint4 (8 bf16 ch),
// one wave-instruction gathers 8 edge rows -> 8x MLP vs scalar gather.
__global__ __launch_bounds__(192) void k_aggr(const int* __restrict__ offs,
        const uint4* __restrict__ aos, const ushort_t* __restrict__ hb,
        const float* __restrict__ bias, const int* __restrict__ batch,
        unsigned* __restrict__ pooled) {
    const int n = blockIdx.x;
    const int tid = threadIdx.x;
    const int head = tid >> 6, lane = tid & 63;
    const int start = offs[n], end = offs[n + 1];
    const char* hbase = (const char*)hb + head * 128 + (lane & 7) * 16;
    const int src0 = lane >> 3;

    float acc[8];
#pragma unroll
    for (int k = 0; k < 8; k++) acc[k] = 0.f;
    float dsum = 0.f;

    for (int cb = start; cb < end; cb += 64) {
        int cnt = end - cb; if (cnt > 64) cnt = 64;
        uint4 rec = aos[cb + lane];             // slack-padded; masked below
        float myexp = 0.f; int myoff = 0;
        if (lane < cnt) {
            myexp = __uint_as_float(head == 0 ? rec.y : (head == 1 ? rec.z : rec.w));
            myoff = (int)rec.x;
        }
        dsum += myexp;
        int groups = (cnt + 7) >> 3;
#pragma unroll 2
        for (int j = 0; j < groups; j++) {
            int sl = j * 8 + src0;
            float a   = __shfl(myexp, sl);      // 0 for padded edges
            int   off = __shfl(myoff, sl);
            uint4 u = *(const uint4*)(hbase + off);
            acc[0] += a * __uint_as_float(u.x << 16);
            acc[1] += a * __uint_as_float(u.x & 0xffff0000u);
            acc[2] += a * __uint_as_float(u.y << 16);
            acc[3] += a * __uint_as_float(u.y & 0xffff0000u);
            acc[4] += a * __uint_as_float(u.z << 16);
            acc[5] += a * __uint_as_float(u.z & 0xffff0000u);
            acc[6] += a * __uint_as_float(u.w << 16);
            acc[7] += a * __uint_as_float(u.w & 0xffff0000u);
        }
    }

#pragma unroll
    for (int m = 1; m < 64; m <<= 1) dsum += __shfl_xor(dsum, m);
#pragma unroll
    for (int k = 0; k < 8; k++) {
        acc[k] += __shfl_xor(acc[k], 8);
        acc[k] += __shfl_xor(acc[k], 16);
        acc[k] += __shfl_xor(acc[k], 32);
    }

    if (lane < 8) {                 // lane owns channels head*64 + lane*8 .. +7
        float inv = 1.f / dsum;
        const int c0 = head * HEAD_DIM + lane * 8;
        unsigned* pp = pooled + batch[n] * HIDDEN + c0;
        const float* bp = bias + c0;
#pragma unroll
        for (int k = 0; k < 8; k++) {
            float v = acc[k] * inv + bp[k];
            v = (v > 0.f) ? v : 0.01f * v;      // F.leaky_relu slope 0.01
            atomicMax(pp + k, f2ord(v));
        }
    }
}

// ---- K6: classifier  logits = pooled @ cls_W + cls_b  (128x2) ----
__global__ __launch_bounds__(256) void k_cls(const unsigned* __restrict__ pooled,
        const float* __restrict__ clsW, const float* __restrict__ clsb,
        float* __restrict__ out) {
    const int t = threadIdx.x;
    const int g = t >> 1, c = t & 1;
    float s = clsb[c];
    for (int fi = 0; fi < HIDDEN; fi++)
        s += ord2f(pooled[g * HIDDEN + fi]) * clsW[fi * NUM_CLASSES + c];
    out[g * NUM_CLASSES + c] = s;
}

extern "C" void kernel_launch(void* const* d_in, const int* in_sizes, int n_in,
                              void* d_out, int out_size, void* d_ws, size_t ws_size,
                              hipStream_t stream) {
    const float* x       = (const float*)d_in[0];
    const int*   ei      = (const int*)d_in[1];   // [2, N_EDGES] flat
    const int*   batch   = (const int*)d_in[2];
    const float* W       = (const float*)d_in[3];
    const float* att_src = (const float*)d_in[4];
    const float* att_dst = (const float*)d_in[5];
    const float* bias    = (const float*)d_in[6];
    const float* clsW    = (const float*)d_in[7];
    const float* clsb    = (const float*)d_in[8];
    float* out = (float*)d_out;

    char* p = (char*)d_ws;
    auto alloc = [&](size_t bytes) {
        char* r = p; p += (bytes + 255) & ~size_t(255); return r;
    };
    ushort_t* hb     = (ushort_t*)alloc(sizeof(ushort_t) * N_NODES * HIDDEN);
    float*    asrc   = (float*)   alloc(sizeof(float) * N_NODES * HEADS);
    float*    adst   = (float*)   alloc(sizeof(float) * N_NODES * HEADS);
    int*      count  = (int*)     alloc(sizeof(int) * N_NODES);
    int*      offs   = (int*)     alloc(sizeof(int) * (N_NODES + 1));
    int*      cursor = (int*)     alloc(sizeof(int) * N_NODES);
    uint4*    aos    = (uint4*)   alloc(sizeof(uint4) * (ETOT + 64));  // +slack
    float*    wsv    = (float*)   alloc(sizeof(float) * F_IN * 6);
    unsigned* pooled = (unsigned*)alloc(sizeof(unsigned) * NUM_GRAPHS * HIDDEN);

    hipMemsetAsync(count, 0, sizeof(int) * N_NODES, stream);
    hipMemsetAsync(pooled, 0, sizeof(unsigned) * NUM_GRAPHS * HIDDEN, stream);

    k_attprep<<<F_IN, 64, 0, stream>>>(W, att_src, att_dst, wsv);
    k_att<<<N_NODES / 4, 256, 0, stream>>>(x, wsv, asrc, adst);
    k_hist<<<(ETOT + 255) / 256, 256, 0, stream>>>(ei, count);
    k_scan<<<1, 1024, 0, stream>>>(count, offs, cursor);
    k_scatter<<<(ETOT + 255) / 256, 256, 0, stream>>>(ei, asrc, adst, cursor, aos);
    k_gemm<<<(N_NODES + 63) / 64, 256, 0, stream>>>(x, W, hb);
    k_aggr<<<N_NODES, 192, 0, stream>>>(offs, aos, hb, bias, batch, pooled);
    k_cls<<<1, 256, 0, stream>>>(pooled, clsW, clsb, out);
}

// Round 5
// 641.419 us; speedup vs baseline: 2.4910x; 2.4910x over previous
//
#include <hip/hip_runtime.h>
#include <math.h>

#define N_NODES   100000
#define N_EDGES   1600000
#define ETOT      1700000   // edges + self loops
#define F_IN      100
#define HEADS     3
#define HEAD_DIM  64
#define HIDDEN    192
#define NUM_GRAPHS 128
#define NUM_CLASSES 2
#define SLAB      256       // nodes per k_pool block

typedef unsigned short ushort_t;

// ---- ordered-uint encoding for float atomicMax (handles negatives) ----
__device__ __forceinline__ unsigned f2ord(float f) {
    unsigned u = __float_as_uint(f);
    return (u & 0x80000000u) ? ~u : (u | 0x80000000u);
}
__device__ __forceinline__ float ord2f(unsigned u) {
    return __uint_as_float((u & 0x80000000u) ? (u & 0x7fffffffu) : ~u);
}
__device__ __forceinline__ unsigned bf16rn(float f) {   // RTNE f32 -> bf16 bits
    unsigned u = __float_as_uint(f);
    return (u + 0x7fffu + ((u >> 16) & 1u)) >> 16;
}

// ---- K1: h = x@W, output bf16. lane=node (64/block), wave=48 features. ----
__global__ __launch_bounds__(256) void k_gemm(
        const float* __restrict__ x, const float* __restrict__ W,
        ushort_t* __restrict__ hb) {
    __shared__ float xs[64 * 101];
    const int tid = threadIdx.x;
    const int lane = tid & 63;
    const int base = blockIdx.x * 64;

    for (int idx = tid; idx < 64 * F_IN; idx += 256) {
        int g = base * F_IN + idx;
        float v = (g < N_NODES * F_IN) ? x[g] : 0.f;
        xs[(idx / F_IN) * 101 + (idx % F_IN)] = v;
    }
    __syncthreads();

    const int f0 = 48 * __builtin_amdgcn_readfirstlane(tid >> 6);

    float acc[48];
#pragma unroll
    for (int i = 0; i < 48; i++) acc[i] = 0.f;

#pragma unroll 2
    for (int k = 0; k < F_IN; k++) {
        float xk = xs[lane * 101 + k];
        const float4* wrow = (const float4*)(W + k * HIDDEN + f0);
#pragma unroll
        for (int fi = 0; fi < 12; fi++) {
            float4 w = wrow[fi];
            acc[fi * 4 + 0] += xk * w.x;
            acc[fi * 4 + 1] += xk * w.y;
            acc[fi * 4 + 2] += xk * w.z;
            acc[fi * 4 + 3] += xk * w.w;
        }
    }

    const int node = base + lane;
    if (node < N_NODES) {
        uint4* hp = (uint4*)(hb + node * HIDDEN + f0);
#pragma unroll
        for (int g = 0; g < 6; g++) {
            uint4 u;
            u.x = bf16rn(acc[g * 8 + 0]) | (bf16rn(acc[g * 8 + 1]) << 16);
            u.y = bf16rn(acc[g * 8 + 2]) | (bf16rn(acc[g * 8 + 3]) << 16);
            u.z = bf16rn(acc[g * 8 + 4]) | (bf16rn(acc[g * 8 + 5]) << 16);
            u.w = bf16rn(acc[g * 8 + 6]) | (bf16rn(acc[g * 8 + 7]) << 16);
            hp[g] = u;
        }
    }
}

// ---- K1b: wsv[k][j] = sum_c W[k][(j%3)*64+c] * att_{src|dst}[j%3][c] ----
__global__ __launch_bounds__(64) void k_attprep(
        const float* __restrict__ W, const float* __restrict__ att_src,
        const float* __restrict__ att_dst, float* __restrict__ wsv) {
    const int k = blockIdx.x;
    const int lane = threadIdx.x;
    float w0 = W[k * HIDDEN + lane];
    float w1 = W[k * HIDDEN + 64 + lane];
    float w2 = W[k * HIDDEN + 128 + lane];
    float p[6];
    p[0] = w0 * att_src[lane];       p[1] = w1 * att_src[64 + lane];
    p[2] = w2 * att_src[128 + lane]; p[3] = w0 * att_dst[lane];
    p[4] = w1 * att_dst[64 + lane];  p[5] = w2 * att_dst[128 + lane];
#pragma unroll
    for (int j = 0; j < 6; j++)
#pragma unroll
        for (int m = 1; m < 64; m <<= 1) p[j] += __shfl_xor(p[j], m);
    if (lane == 0) {
#pragma unroll
        for (int j = 0; j < 6; j++) wsv[k * 6 + j] = p[j];
    }
}

// ---- K1c: asrc/adst = x @ wsv  (wave per node, coalesced x reads) ----
__global__ __launch_bounds__(256) void k_att(
        const float* __restrict__ x, const float* __restrict__ wsv,
        float* __restrict__ asrc, float* __restrict__ adst) {
    const int lane = threadIdx.x & 63;
    const int nid = blockIdx.x * 4 + (threadIdx.x >> 6);
    float xv0 = x[nid * F_IN + lane];
    int l2 = (lane < F_IN - 64) ? (64 + lane) : 0;
    float xv1 = (lane < F_IN - 64) ? x[nid * F_IN + 64 + lane] : 0.f;
    float p[6];
#pragma unroll
    for (int j = 0; j < 6; j++)
        p[j] = xv0 * wsv[lane * 6 + j] + xv1 * wsv[l2 * 6 + j];
#pragma unroll
    for (int j = 0; j < 6; j++)
#pragma unroll
        for (int msk = 1; msk < 64; msk <<= 1)
            p[j] += __shfl_xor(p[j], msk);
    if (lane < 3) {
        asrc[nid * HEADS + lane] = p[lane];
        adst[nid * HEADS + lane] = p[3 + lane];
    }
}

// ---- K2: histogram of incoming-edge counts per dst ----
__global__ void k_hist(const int* __restrict__ ei, int* __restrict__ count) {
    int i = blockIdx.x * blockDim.x + threadIdx.x;
    if (i >= ETOT) return;
    int d = (i < N_EDGES) ? ei[N_EDGES + i] : (i - N_EDGES);
    atomicAdd(&count[d], 1);
}

// ---- K3: exclusive scan, wave-parallel two-phase (single block) ----
__global__ __launch_bounds__(1024) void k_scan(
        const int* __restrict__ count, int* __restrict__ offs, int* __restrict__ cursor) {
    __shared__ int wsum[16];
    __shared__ int wexc[16];
    const int t = threadIdx.x, w = t >> 6, lane = t & 63;
    const int CH = N_NODES / 16;            // 6250, exact
    const int begin = w * CH, end = begin + CH;

    int s = 0;
    for (int i = begin + lane; i < end; i += 64) s += count[i];
#pragma unroll
    for (int off = 32; off; off >>= 1) s += __shfl_down(s, off);
    if (lane == 0) wsum[w] = s;
    __syncthreads();
    if (t == 0) {
        int run = 0;
        for (int i = 0; i < 16; i++) { wexc[i] = run; run += wsum[i]; }
        offs[N_NODES] = run;
    }
    __syncthreads();

    int running = wexc[w];
    for (int cb = begin; cb < end; cb += 64) {
        int i = cb + lane;
        int v = (i < end) ? count[i] : 0;
        int sc = v;
#pragma unroll
        for (int off = 1; off < 64; off <<= 1) {
            int u = __shfl_up(sc, off);
            if (lane >= off) sc += u;
        }
        if (i < end) { int e = running + sc - v; offs[i] = e; cursor[i] = e; }
        running += __shfl(sc, 63);
    }
}

// ---- K4: scatter into dst-sorted AoS {src_byte_off, exp(e0), exp(e1), exp(e2)} ----
__global__ void k_scatter(const int* __restrict__ ei,
        const float* __restrict__ asrc, const float* __restrict__ adst,
        int* __restrict__ cursor, uint4* __restrict__ aos) {
    int i = blockIdx.x * blockDim.x + threadIdx.x;
    if (i >= ETOT) return;
    int s, d;
    if (i < N_EDGES) { s = ei[i]; d = ei[N_EDGES + i]; }
    else             { s = d = i - N_EDGES; }
    int pos = atomicAdd(&cursor[d], 1);
    float e[HEADS];
#pragma unroll
    for (int hh = 0; hh < HEADS; hh++) {
        float v = asrc[s * HEADS + hh] + adst[d * HEADS + hh];
        v = (v > 0.f) ? v : 0.2f * v;       // leaky_relu slope 0.2
        e[hh] = expf(v);                    // max-free softmax numerator
    }
    uint4 rec;
    rec.x = (unsigned)(s * (HIDDEN * 2));   // byte offset of bf16 row
    rec.y = __float_as_uint(e[0]);
    rec.z = __float_as_uint(e[1]);
    rec.w = __float_as_uint(e[2]);
    aos[pos] = rec;
}

// ---- K5: softmax-aggregate + bias + leaky_relu -> o[n][192] (NO atomics) ----
// wave = (node, head). 8 lanes per edge-row: lane loads uint4 (8 bf16 ch),
// one wave-instruction gathers 8 independent edge rows.
__global__ __launch_bounds__(192) void k_aggr(const int* __restrict__ offs,
        const uint4* __restrict__ aos, const ushort_t* __restrict__ hb,
        const float* __restrict__ bias, float* __restrict__ o) {
    const int n = blockIdx.x;
    const int tid = threadIdx.x;
    const int head = tid >> 6, lane = tid & 63;
    const int start = offs[n], end = offs[n + 1];
    const char* hbase = (const char*)hb + head * 128 + (lane & 7) * 16;
    const int src0 = lane >> 3;

    float acc[8];
#pragma unroll
    for (int k = 0; k < 8; k++) acc[k] = 0.f;
    float dsum = 0.f;

    for (int cb = start; cb < end; cb += 64) {
        int cnt = end - cb; if (cnt > 64) cnt = 64;
        uint4 rec = aos[cb + lane];             // slack-padded; masked below
        float myexp = 0.f; int myoff = 0;
        if (lane < cnt) {
            myexp = __uint_as_float(head == 0 ? rec.y : (head == 1 ? rec.z : rec.w));
            myoff = (int)rec.x;
        }
        dsum += myexp;
        int groups = (cnt + 7) >> 3;
#pragma unroll 2
        for (int j = 0; j < groups; j++) {
            int sl = j * 8 + src0;
            float a   = __shfl(myexp, sl);      // 0 for padded edges
            int   off = __shfl(myoff, sl);
            uint4 u = *(const uint4*)(hbase + off);
            acc[0] += a * __uint_as_float(u.x << 16);
            acc[1] += a * __uint_as_float(u.x & 0xffff0000u);
            acc[2] += a * __uint_as_float(u.y << 16);
            acc[3] += a * __uint_as_float(u.y & 0xffff0000u);
            acc[4] += a * __uint_as_float(u.z << 16);
            acc[5] += a * __uint_as_float(u.z & 0xffff0000u);
            acc[6] += a * __uint_as_float(u.w << 16);
            acc[7] += a * __uint_as_float(u.w & 0xffff0000u);
        }
    }

#pragma unroll
    for (int m = 1; m < 64; m <<= 1) dsum += __shfl_xor(dsum, m);
#pragma unroll
    for (int k = 0; k < 8; k++) {
        acc[k] += __shfl_xor(acc[k], 8);
        acc[k] += __shfl_xor(acc[k], 16);
        acc[k] += __shfl_xor(acc[k], 32);
    }

    if (lane < 8) {                 // lane owns channels head*64 + lane*8 .. +7
        const float inv = 1.f / dsum;
        const int c0 = head * HEAD_DIM + lane * 8;
        const float* bp = bias + c0;
        float v[8];
#pragma unroll
        for (int k = 0; k < 8; k++) {
            float t = acc[k] * inv + bp[k];
            v[k] = (t > 0.f) ? t : 0.01f * t;   // F.leaky_relu slope 0.01
        }
        float4* op = (float4*)(o + n * HIDDEN + c0);
        op[0] = make_float4(v[0], v[1], v[2], v[3]);
        op[1] = make_float4(v[4], v[5], v[6], v[7]);
    }
}

// ---- K5b: slab-wise max-pool over sorted batch -> few coalesced atomics ----
// block = 192 threads (thread == channel), SLAB nodes per block
__global__ __launch_bounds__(192) void k_pool(
        const float* __restrict__ o, const int* __restrict__ batch,
        unsigned* __restrict__ pooled) {
    const int t = threadIdx.x;
    const int n0 = blockIdx.x * SLAB;
    int n1 = n0 + SLAB; if (n1 > N_NODES) n1 = N_NODES;
    int curg = batch[n0];
    float m = -INFINITY;
    for (int n = n0; n < n1; n++) {
        int g = batch[n];                   // wave-uniform broadcast load
        if (g != curg) {                    // graph boundary: flush local max
            atomicMax(&pooled[curg * HIDDEN + t], f2ord(m));
            m = -INFINITY; curg = g;
        }
        m = fmaxf(m, o[n * HIDDEN + t]);
    }
    atomicMax(&pooled[curg * HIDDEN + t], f2ord(m));
}

// ---- K6: classifier  logits = pooled @ cls_W + cls_b  (128x2) ----
__global__ __launch_bounds__(256) void k_cls(const unsigned* __restrict__ pooled,
        const float* __restrict__ clsW, const float* __restrict__ clsb,
        float* __restrict__ out) {
    const int t = threadIdx.x;
    const int g = t >> 1, c = t & 1;
    float s = clsb[c];
    for (int fi = 0; fi < HIDDEN; fi++)
        s += ord2f(pooled[g * HIDDEN + fi]) * clsW[fi * NUM_CLASSES + c];
    out[g * NUM_CLASSES + c] = s;
}

extern "C" void kernel_launch(void* const* d_in, const int* in_sizes, int n_in,
                              void* d_out, int out_size, void* d_ws, size_t ws_size,
                              hipStream_t stream) {
    const float* x       = (const float*)d_in[0];
    const int*   ei      = (const int*)d_in[1];   // [2, N_EDGES] flat
    const int*   batch   = (const int*)d_in[2];
    const float* W       = (const float*)d_in[3];
    const float* att_src = (const float*)d_in[4];
    const float* att_dst = (const float*)d_in[5];
    const float* bias    = (const float*)d_in[6];
    const float* clsW    = (const float*)d_in[7];
    const float* clsb    = (const float*)d_in[8];
    float* out = (float*)d_out;

    char* p = (char*)d_ws;
    auto alloc = [&](size_t bytes) {
        char* r = p; p += (bytes + 255) & ~size_t(255); return r;
    };
    ushort_t* hb     = (ushort_t*)alloc(sizeof(ushort_t) * N_NODES * HIDDEN);
    float*    o      = (float*)   alloc(sizeof(float) * N_NODES * HIDDEN);
    float*    asrc   = (float*)   alloc(sizeof(float) * N_NODES * HEADS);
    float*    adst   = (float*)   alloc(sizeof(float) * N_NODES * HEADS);
    int*      count  = (int*)     alloc(sizeof(int) * N_NODES);
    int*      offs   = (int*)     alloc(sizeof(int) * (N_NODES + 1));
    int*      cursor = (int*)     alloc(sizeof(int) * N_NODES);
    uint4*    aos    = (uint4*)   alloc(sizeof(uint4) * (ETOT + 64));  // +slack
    float*    wsv    = (float*)   alloc(sizeof(float) * F_IN * 6);
    unsigned* pooled = (unsigned*)alloc(sizeof(unsigned) * NUM_GRAPHS * HIDDEN);

    hipMemsetAsync(count, 0, sizeof(int) * N_NODES, stream);
    hipMemsetAsync(pooled, 0, sizeof(unsigned) * NUM_GRAPHS * HIDDEN, stream);

    k_attprep<<<F_IN, 64, 0, stream>>>(W, att_src, att_dst, wsv);
    k_att<<<N_NODES / 4, 256, 0, stream>>>(x, wsv, asrc, adst);
    k_hist<<<(ETOT + 255) / 256, 256, 0, stream>>>(ei, count);
    k_scan<<<1, 1024, 0, stream>>>(count, offs, cursor);
    k_scatter<<<(ETOT + 255) / 256, 256, 0, stream>>>(ei, asrc, adst, cursor, aos);
    k_gemm<<<(N_NODES + 63) / 64, 256, 0, stream>>>(x, W, hb);
    k_aggr<<<N_NODES, 192, 0, stream>>>(offs, aos, hb, bias, o);
    k_pool<<<(N_NODES + SLAB - 1) / SLAB, 192, 0, stream>>>(o, batch, pooled);
    k_cls<<<1, 256, 0, stream>>>(pooled, clsW, clsb, out);
}

// Round 6
// 572.925 us; speedup vs baseline: 2.7888x; 1.1196x over previous
//
#include <hip/hip_runtime.h>
#include <math.h>

#define N_NODES   100000
#define N_EDGES   1600000
#define ETOT      1700000   // edges + self loops
#define F_IN      100
#define HEADS     3
#define HEAD_DIM  64
#define HIDDEN    192
#define NUM_GRAPHS 128
#define NUM_CLASSES 2
#define SLAB      256       // nodes per k_pool block
#define WT_COLS   208       // 192 h-cols + 6 att-cols + 2 pad-tiles... (13*16)
#define KPAD      128       // K padded to 4 chunks of 32

typedef unsigned short ushort_t;
typedef __attribute__((ext_vector_type(8))) short short8;
typedef __attribute__((ext_vector_type(4))) float floatx4;

// ---- ordered-uint encoding for float atomicMax (handles negatives) ----
__device__ __forceinline__ unsigned f2ord(float f) {
    unsigned u = __float_as_uint(f);
    return (u & 0x80000000u) ? ~u : (u | 0x80000000u);
}
__device__ __forceinline__ float ord2f(unsigned u) {
    return __uint_as_float((u & 0x80000000u) ? (u & 0x7fffffffu) : ~u);
}
__device__ __forceinline__ unsigned bf16rn(float f) {   // RTNE f32 -> bf16 bits
    unsigned u = __float_as_uint(f);
    return (u + 0x7fffu + ((u >> 16) & 1u)) >> 16;
}

// ---- K0: prep — wsv = W@att (6 cols), build transposed hi/lo bf16 W ----
// WT[col][k], col 0..191 = W, col 192..197 = wsv, rest/k>=100 zero.
__global__ __launch_bounds__(256) void k_prep(
        const float* __restrict__ W, const float* __restrict__ att_src,
        const float* __restrict__ att_dst,
        ushort_t* __restrict__ WT_hi, ushort_t* __restrict__ WT_lo) {
    __shared__ float wsv_s[F_IN * 6];
    const int t = threadIdx.x;
    for (int p = t; p < F_IN * 6; p += 256) {
        int k = p / 6, j = p % 6;
        const float* a = (j < 3) ? att_src : att_dst;
        int hh = j % 3;
        float s = 0.f;
        for (int c = 0; c < HEAD_DIM; c++)
            s += W[k * HIDDEN + hh * HEAD_DIM + c] * a[hh * HEAD_DIM + c];
        wsv_s[p] = s;
    }
    __syncthreads();
    for (int idx = t; idx < WT_COLS * KPAD; idx += 256) {
        int col = idx >> 7, k = idx & (KPAD - 1);
        float v = 0.f;
        if (k < F_IN) {
            if (col < HIDDEN) v = W[k * HIDDEN + col];
            else if (col < HIDDEN + 6) v = wsv_s[k * 6 + (col - HIDDEN)];
        }
        unsigned hi = bf16rn(v);
        WT_hi[idx] = (ushort_t)hi;
        float lo = v - __uint_as_float(hi << 16);
        WT_lo[idx] = (ushort_t)bf16rn(lo);
    }
}

// ---- K1: h = x@W via MFMA (bf16 hi/lo 3-term split ~ fp32 accuracy) ----
// block = 256 thr (4 waves), 16 nodes. Wave w: col-tiles {3w..} (w3: 4 tiles,
// tile 12 = att cols -> asrc/adst). x tile staged to LDS as bf16 hi/lo.
__global__ __launch_bounds__(256) void k_gemm(
        const float* __restrict__ x,
        const ushort_t* __restrict__ WT_hi, const ushort_t* __restrict__ WT_lo,
        ushort_t* __restrict__ hb,
        float* __restrict__ asrc, float* __restrict__ adst) {
    __shared__ ushort_t xs_hi[16 * 136];   // stride 136 (pad 8) vs bank conflicts
    __shared__ ushort_t xs_lo[16 * 136];
    const int tid = threadIdx.x;
    const int base = blockIdx.x * 16;

    for (int idx = tid; idx < 16 * KPAD; idx += 256) {
        int row = idx >> 7, k = idx & (KPAD - 1);
        float v = (k < F_IN) ? x[(base + row) * F_IN + k] : 0.f;
        unsigned hi = bf16rn(v);
        xs_hi[row * 136 + k] = (ushort_t)hi;
        float lo = v - __uint_as_float(hi << 16);
        xs_lo[row * 136 + k] = (ushort_t)bf16rn(lo);
    }
    __syncthreads();

    const int wid = tid >> 6, l = tid & 63;
    const int row16 = l & 15, g = l >> 4;          // A row, k-quad
    const int NT = (wid == 3) ? 4 : 3;
    const int t0 = (wid == 3) ? 9 : wid * 3;

    floatx4 acc[4];
#pragma unroll
    for (int i = 0; i < 4; i++) acc[i] = (floatx4)0.f;

#pragma unroll
    for (int c = 0; c < 4; c++) {                  // K chunks of 32
        const int ke = g * 8 + c * 32;             // element offset in k
        short8 ah = *(const short8*)(xs_hi + row16 * 136 + ke);
        short8 al = *(const short8*)(xs_lo + row16 * 136 + ke);
#pragma unroll
        for (int ti = 0; ti < 4; ti++) {
            if (ti >= NT) break;
            const int col = (t0 + ti) * 16 + row16;
            short8 bh = *(const short8*)(WT_hi + col * KPAD + ke);
            short8 bl = *(const short8*)(WT_lo + col * KPAD + ke);
            acc[ti] = __builtin_amdgcn_mfma_f32_16x16x32_bf16(ah, bh, acc[ti], 0, 0, 0);
            acc[ti] = __builtin_amdgcn_mfma_f32_16x16x32_bf16(ah, bl, acc[ti], 0, 0, 0);
            acc[ti] = __builtin_amdgcn_mfma_f32_16x16x32_bf16(al, bh, acc[ti], 0, 0, 0);
        }
    }

    // epilogue: C/D layout col=l&15, row=g*4+r  (m89-verified)
#pragma unroll
    for (int ti = 0; ti < 4; ti++) {
        if (ti >= NT) break;
        const int tile = t0 + ti;
        if (tile < 12) {
#pragma unroll
            for (int r = 0; r < 4; r++) {
                int node = base + g * 4 + r;
                hb[node * HIDDEN + tile * 16 + row16] = (ushort_t)bf16rn(acc[ti][r]);
            }
        } else {                                   // att cols 192..197
            if (row16 < 6) {
#pragma unroll
                for (int r = 0; r < 4; r++) {
                    int node = base + g * 4 + r;
                    if (row16 < 3) asrc[node * HEADS + row16] = acc[ti][r];
                    else           adst[node * HEADS + (row16 - 3)] = acc[ti][r];
                }
            }
        }
    }
}

// ---- K2: histogram of incoming-edge counts per dst ----
__global__ void k_hist(const int* __restrict__ ei, int* __restrict__ count) {
    int i = blockIdx.x * blockDim.x + threadIdx.x;
    if (i >= ETOT) return;
    int d = (i < N_EDGES) ? ei[N_EDGES + i] : (i - N_EDGES);
    atomicAdd(&count[d], 1);
}

// ---- K3a/b/c: device-wide exclusive scan of count -> offs, cursor ----
__global__ __launch_bounds__(256) void k_scan1(
        const int* __restrict__ count, int* __restrict__ bsum) {
    __shared__ int ws[4];
    const int t = threadIdx.x, wid = t >> 6, lane = t & 63;
    int i = blockIdx.x * 256 + t;
    int v = (i < N_NODES) ? count[i] : 0;
#pragma unroll
    for (int off = 32; off; off >>= 1) v += __shfl_down(v, off);
    if (lane == 0) ws[wid] = v;
    __syncthreads();
    if (t == 0) bsum[blockIdx.x] = ws[0] + ws[1] + ws[2] + ws[3];
}

__global__ __launch_bounds__(64) void k_scan2(
        const int* __restrict__ bsum, int* __restrict__ bexc,
        int* __restrict__ offs, int nblk) {
    const int lane = threadIdx.x;
    int run = 0;
    for (int cb = 0; cb < nblk; cb += 64) {
        int i = cb + lane;
        int v = (i < nblk) ? bsum[i] : 0;
        int sc = v;
#pragma unroll
        for (int off = 1; off < 64; off <<= 1) {
            int u = __shfl_up(sc, off);
            if (lane >= off) sc += u;
        }
        if (i < nblk) bexc[i] = run + sc - v;
        run += __shfl(sc, 63);
    }
    if (lane == 0) offs[N_NODES] = run;
}

__global__ __launch_bounds__(256) void k_scan3(
        const int* __restrict__ count, const int* __restrict__ bexc,
        int* __restrict__ offs, int* __restrict__ cursor) {
    __shared__ int ws[4];
    const int t = threadIdx.x, wid = t >> 6, lane = t & 63;
    int i = blockIdx.x * 256 + t;
    int v = (i < N_NODES) ? count[i] : 0;
    int sc = v;
#pragma unroll
    for (int off = 1; off < 64; off <<= 1) {
        int u = __shfl_up(sc, off);
        if (lane >= off) sc += u;
    }
    if (lane == 63) ws[wid] = sc;
    __syncthreads();
    if (t == 0) {
        int run = 0;
#pragma unroll
        for (int j = 0; j < 4; j++) { int tmp = ws[j]; ws[j] = run; run += tmp; }
    }
    __syncthreads();
    if (i < N_NODES) {
        int e = bexc[blockIdx.x] + ws[wid] + sc - v;
        offs[i] = e; cursor[i] = e;
    }
}

// ---- K4: scatter into dst-sorted AoS {src_byte_off, exp(e0), exp(e1), exp(e2)} ----
__global__ void k_scatter(const int* __restrict__ ei,
        const float* __restrict__ asrc, const float* __restrict__ adst,
        int* __restrict__ cursor, uint4* __restrict__ aos) {
    int i = blockIdx.x * blockDim.x + threadIdx.x;
    if (i >= ETOT) return;
    int s, d;
    if (i < N_EDGES) { s = ei[i]; d = ei[N_EDGES + i]; }
    else             { s = d = i - N_EDGES; }
    int pos = atomicAdd(&cursor[d], 1);
    float e[HEADS];
#pragma unroll
    for (int hh = 0; hh < HEADS; hh++) {
        float v = asrc[s * HEADS + hh] + adst[d * HEADS + hh];
        v = (v > 0.f) ? v : 0.2f * v;       // leaky_relu slope 0.2
        e[hh] = expf(v);                    // max-free softmax numerator
    }
    uint4 rec;
    rec.x = (unsigned)(s * (HIDDEN * 2));   // byte offset of bf16 row
    rec.y = __float_as_uint(e[0]);
    rec.z = __float_as_uint(e[1]);
    rec.w = __float_as_uint(e[2]);
    aos[pos] = rec;
}

// ---- K5: softmax-aggregate + bias + leaky_relu -> ob[n][192] bf16 ----
__global__ __launch_bounds__(192) void k_aggr(const int* __restrict__ offs,
        const uint4* __restrict__ aos, const ushort_t* __restrict__ hb,
        const float* __restrict__ bias, ushort_t* __restrict__ ob) {
    const int n = blockIdx.x;
    const int tid = threadIdx.x;
    const int head = tid >> 6, lane = tid & 63;
    const int start = offs[n], end = offs[n + 1];
    const char* hbase = (const char*)hb + head * 128 + (lane & 7) * 16;
    const int src0 = lane >> 3;

    float acc[8];
#pragma unroll
    for (int k = 0; k < 8; k++) acc[k] = 0.f;
    float dsum = 0.f;

    for (int cb = start; cb < end; cb += 64) {
        int cnt = end - cb; if (cnt > 64) cnt = 64;
        uint4 rec = aos[cb + lane];             // slack-padded; masked below
        float myexp = 0.f; int myoff = 0;
        if (lane < cnt) {
            myexp = __uint_as_float(head == 0 ? rec.y : (head == 1 ? rec.z : rec.w));
            myoff = (int)rec.x;
        }
        dsum += myexp;
        int groups = (cnt + 7) >> 3;
#pragma unroll 2
        for (int j = 0; j < groups; j++) {
            int sl = j * 8 + src0;
            float a   = __shfl(myexp, sl);      // 0 for padded edges
            int   off = __shfl(myoff, sl);
            uint4 u = *(const uint4*)(hbase + off);
            acc[0] += a * __uint_as_float(u.x << 16);
            acc[1] += a * __uint_as_float(u.x & 0xffff0000u);
            acc[2] += a * __uint_as_float(u.y << 16);
            acc[3] += a * __uint_as_float(u.y & 0xffff0000u);
            acc[4] += a * __uint_as_float(u.z << 16);
            acc[5] += a * __uint_as_float(u.z & 0xffff0000u);
            acc[6] += a * __uint_as_float(u.w << 16);
            acc[7] += a * __uint_as_float(u.w & 0xffff0000u);
        }
    }

#pragma unroll
    for (int m = 1; m < 64; m <<= 1) dsum += __shfl_xor(dsum, m);
#pragma unroll
    for (int k = 0; k < 8; k++) {
        acc[k] += __shfl_xor(acc[k], 8);
        acc[k] += __shfl_xor(acc[k], 16);
        acc[k] += __shfl_xor(acc[k], 32);
    }

    if (lane < 8) {                 // lane owns channels head*64 + lane*8 .. +7
        const float inv = 1.f / dsum;
        const int c0 = head * HEAD_DIM + lane * 8;
        const float* bp = bias + c0;
        unsigned pk[4];
#pragma unroll
        for (int q = 0; q < 4; q++) {
            float v0 = acc[2 * q] * inv + bp[2 * q];
            float v1 = acc[2 * q + 1] * inv + bp[2 * q + 1];
            v0 = (v0 > 0.f) ? v0 : 0.01f * v0;
            v1 = (v1 > 0.f) ? v1 : 0.01f * v1;
            pk[q] = bf16rn(v0) | (bf16rn(v1) << 16);
        }
        *(uint4*)(ob + n * HIDDEN + c0) = make_uint4(pk[0], pk[1], pk[2], pk[3]);
    }
}

// ---- K5b: slab-wise max-pool over sorted batch -> few coalesced atomics ----
__global__ __launch_bounds__(192) void k_pool(
        const ushort_t* __restrict__ ob, const int* __restrict__ batch,
        unsigned* __restrict__ pooled) {
    const int t = threadIdx.x;
    const int n0 = blockIdx.x * SLAB;
    int n1 = n0 + SLAB; if (n1 > N_NODES) n1 = N_NODES;
    int curg = batch[n0];
    float m = -INFINITY;
    for (int n = n0; n < n1; n++) {
        int g = batch[n];                   // wave-uniform broadcast load
        if (g != curg) {                    // graph boundary: flush local max
            atomicMax(&pooled[curg * HIDDEN + t], f2ord(m));
            m = -INFINITY; curg = g;
        }
        m = fmaxf(m, __uint_as_float((unsigned)ob[n * HIDDEN + t] << 16));
    }
    atomicMax(&pooled[curg * HIDDEN + t], f2ord(m));
}

// ---- K6: classifier  logits = pooled @ cls_W + cls_b  (128x2) ----
__global__ __launch_bounds__(256) void k_cls(const unsigned* __restrict__ pooled,
        const float* __restrict__ clsW, const float* __restrict__ clsb,
        float* __restrict__ out) {
    const int t = threadIdx.x;
    const int g = t >> 1, c = t & 1;
    float s = clsb[c];
    for (int fi = 0; fi < HIDDEN; fi++)
        s += ord2f(pooled[g * HIDDEN + fi]) * clsW[fi * NUM_CLASSES + c];
    out[g * NUM_CLASSES + c] = s;
}

extern "C" void kernel_launch(void* const* d_in, const int* in_sizes, int n_in,
                              void* d_out, int out_size, void* d_ws, size_t ws_size,
                              hipStream_t stream) {
    const float* x       = (const float*)d_in[0];
    const int*   ei      = (const int*)d_in[1];   // [2, N_EDGES] flat
    const int*   batch   = (const int*)d_in[2];
    const float* W       = (const float*)d_in[3];
    const float* att_src = (const float*)d_in[4];
    const float* att_dst = (const float*)d_in[5];
    const float* bias    = (const float*)d_in[6];
    const float* clsW    = (const float*)d_in[7];
    const float* clsb    = (const float*)d_in[8];
    float* out = (float*)d_out;

    const int NBLK = (N_NODES + 255) / 256;   // 391 scan blocks

    char* p = (char*)d_ws;
    auto alloc = [&](size_t bytes) {
        char* r = p; p += (bytes + 255) & ~size_t(255); return r;
    };
    ushort_t* hb     = (ushort_t*)alloc(sizeof(ushort_t) * N_NODES * HIDDEN);
    ushort_t* ob     = (ushort_t*)alloc(sizeof(ushort_t) * N_NODES * HIDDEN);
    float*    asrc   = (float*)   alloc(sizeof(float) * N_NODES * HEADS);
    float*    adst   = (float*)   alloc(sizeof(float) * N_NODES * HEADS);
    int*      count  = (int*)     alloc(sizeof(int) * N_NODES);
    int*      offs   = (int*)     alloc(sizeof(int) * (N_NODES + 1));
    int*      cursor = (int*)     alloc(sizeof(int) * N_NODES);
    int*      bsum   = (int*)     alloc(sizeof(int) * NBLK);
    int*      bexc   = (int*)     alloc(sizeof(int) * NBLK);
    uint4*    aos    = (uint4*)   alloc(sizeof(uint4) * (ETOT + 64));  // +slack
    ushort_t* WT_hi  = (ushort_t*)alloc(sizeof(ushort_t) * WT_COLS * KPAD);
    ushort_t* WT_lo  = (ushort_t*)alloc(sizeof(ushort_t) * WT_COLS * KPAD);
    unsigned* pooled = (unsigned*)alloc(sizeof(unsigned) * NUM_GRAPHS * HIDDEN);

    hipMemsetAsync(count, 0, sizeof(int) * N_NODES, stream);
    hipMemsetAsync(pooled, 0, sizeof(unsigned) * NUM_GRAPHS * HIDDEN, stream);

    k_prep<<<1, 256, 0, stream>>>(W, att_src, att_dst, WT_hi, WT_lo);
    k_gemm<<<N_NODES / 16, 256, 0, stream>>>(x, WT_hi, WT_lo, hb, asrc, adst);
    k_hist<<<(ETOT + 255) / 256, 256, 0, stream>>>(ei, count);
    k_scan1<<<NBLK, 256, 0, stream>>>(count, bsum);
    k_scan2<<<1, 64, 0, stream>>>(bsum, bexc, offs, NBLK);
    k_scan3<<<NBLK, 256, 0, stream>>>(count, bexc, offs, cursor);
    k_scatter<<<(ETOT + 255) / 256, 256, 0, stream>>>(ei, asrc, adst, cursor, aos);
    k_aggr<<<N_NODES, 192, 0, stream>>>(offs, aos, hb, bias, ob);
    k_pool<<<(N_NODES + SLAB - 1) / SLAB, 192, 0, stream>>>(ob, batch, pooled);
    k_cls<<<1, 256, 0, stream>>>(pooled, clsW, clsb, out);
}

// Round 7
// 505.302 us; speedup vs baseline: 3.1620x; 1.1338x over previous
//
#include <hip/hip_runtime.h>
#include <math.h>

#define N_NODES   100000
#define N_EDGES   1600000
#define ETOT      1700000   // edges + self loops
#define EHALF     850000
#define F_IN      100
#define HEADS     3
#define HEAD_DIM  64
#define HIDDEN    192
#define NUM_GRAPHS 128
#define NUM_CLASSES 2
#define SLAB      64        // nodes per k_pool block
#define WT_COLS   208       // 13 col-tiles of 16 (192 h + 6 att + pad)
#define KPAD      128       // K padded to 4 chunks of 32

typedef unsigned short ushort_t;
typedef __attribute__((ext_vector_type(8))) short short8;
typedef __attribute__((ext_vector_type(4))) float floatx4;

// ---- ordered-uint encoding for float atomicMax (handles negatives) ----
__device__ __forceinline__ unsigned f2ord(float f) {
    unsigned u = __float_as_uint(f);
    return (u & 0x80000000u) ? ~u : (u | 0x80000000u);
}
__device__ __forceinline__ float ord2f(unsigned u) {
    return __uint_as_float((u & 0x80000000u) ? (u & 0x7fffffffu) : ~u);
}
__device__ __forceinline__ unsigned bf16rn(float f) {   // RTNE f32 -> bf16 bits
    unsigned u = __float_as_uint(f);
    return (u + 0x7fffu + ((u >> 16) & 1u)) >> 16;
}

// ---- K0: prep — wsv = W@att (6 cols), build transposed hi/lo bf16 W ----
__global__ __launch_bounds__(256) void k_prep(
        const float* __restrict__ W, const float* __restrict__ att_src,
        const float* __restrict__ att_dst,
        ushort_t* __restrict__ WT_hi, ushort_t* __restrict__ WT_lo) {
    __shared__ float wsv_s[F_IN * 6];
    const int t = threadIdx.x;
    for (int p = t; p < F_IN * 6; p += 256) {
        int k = p / 6, j = p % 6;
        const float* a = (j < 3) ? att_src : att_dst;
        int hh = j % 3;
        float s = 0.f;
        for (int c = 0; c < HEAD_DIM; c++)
            s += W[k * HIDDEN + hh * HEAD_DIM + c] * a[hh * HEAD_DIM + c];
        wsv_s[p] = s;
    }
    __syncthreads();
    for (int idx = t; idx < WT_COLS * KPAD; idx += 256) {
        int col = idx >> 7, k = idx & (KPAD - 1);
        float v = 0.f;
        if (k < F_IN) {
            if (col < HIDDEN) v = W[k * HIDDEN + col];
            else if (col < HIDDEN + 6) v = wsv_s[k * 6 + (col - HIDDEN)];
        }
        unsigned hi = bf16rn(v);
        WT_hi[idx] = (ushort_t)hi;
        float lo = v - __uint_as_float(hi << 16);
        WT_lo[idx] = (ushort_t)bf16rn(lo);
    }
}

// ---- K1: h = x@W via MFMA, 32-node M-tile (2 M-halves share B-frags) ----
__global__ __launch_bounds__(256) void k_gemm(
        const float* __restrict__ x,
        const ushort_t* __restrict__ WT_hi, const ushort_t* __restrict__ WT_lo,
        ushort_t* __restrict__ hb,
        float* __restrict__ asrc, float* __restrict__ adst) {
    __shared__ ushort_t xs_hi[32 * 136];
    __shared__ ushort_t xs_lo[32 * 136];
    const int tid = threadIdx.x;
    const int base = blockIdx.x * 32;

    for (int idx = tid; idx < 32 * KPAD; idx += 256) {
        int row = idx >> 7, k = idx & (KPAD - 1);
        float v = (k < F_IN) ? x[(base + row) * F_IN + k] : 0.f;
        unsigned hi = bf16rn(v);
        xs_hi[row * 136 + k] = (ushort_t)hi;
        float lo = v - __uint_as_float(hi << 16);
        xs_lo[row * 136 + k] = (ushort_t)bf16rn(lo);
    }
    __syncthreads();

    const int wid = tid >> 6, l = tid & 63;
    const int row16 = l & 15, g = l >> 4;          // col-in-tile, k-quad
    const int NT = (wid == 3) ? 4 : 3;
    const int t0 = wid * 3;

    floatx4 acc[2][4];
#pragma unroll
    for (int m = 0; m < 2; m++)
#pragma unroll
        for (int i = 0; i < 4; i++) acc[m][i] = (floatx4)0.f;

#pragma unroll
    for (int c = 0; c < 4; c++) {                  // K chunks of 32
        const int ke = g * 8 + c * 32;
        short8 ah0 = *(const short8*)(xs_hi + row16 * 136 + ke);
        short8 al0 = *(const short8*)(xs_lo + row16 * 136 + ke);
        short8 ah1 = *(const short8*)(xs_hi + (16 + row16) * 136 + ke);
        short8 al1 = *(const short8*)(xs_lo + (16 + row16) * 136 + ke);
#pragma unroll
        for (int ti = 0; ti < 4; ti++) {
            if (ti >= NT) break;
            const int col = (t0 + ti) * 16 + row16;
            short8 bh = *(const short8*)(WT_hi + col * KPAD + ke);
            short8 bl = *(const short8*)(WT_lo + col * KPAD + ke);
            acc[0][ti] = __builtin_amdgcn_mfma_f32_16x16x32_bf16(ah0, bh, acc[0][ti], 0, 0, 0);
            acc[0][ti] = __builtin_amdgcn_mfma_f32_16x16x32_bf16(ah0, bl, acc[0][ti], 0, 0, 0);
            acc[0][ti] = __builtin_amdgcn_mfma_f32_16x16x32_bf16(al0, bh, acc[0][ti], 0, 0, 0);
            acc[1][ti] = __builtin_amdgcn_mfma_f32_16x16x32_bf16(ah1, bh, acc[1][ti], 0, 0, 0);
            acc[1][ti] = __builtin_amdgcn_mfma_f32_16x16x32_bf16(ah1, bl, acc[1][ti], 0, 0, 0);
            acc[1][ti] = __builtin_amdgcn_mfma_f32_16x16x32_bf16(al1, bh, acc[1][ti], 0, 0, 0);
        }
    }

    // epilogue: C/D layout col=row16, row=g*4+r (m89-verified)
#pragma unroll
    for (int ti = 0; ti < 4; ti++) {
        if (ti >= NT) break;
        const int tile = t0 + ti;
        if (tile < 12) {
#pragma unroll
            for (int m = 0; m < 2; m++)
#pragma unroll
                for (int r = 0; r < 4; r++) {
                    int node = base + m * 16 + g * 4 + r;
                    hb[node * HIDDEN + tile * 16 + row16] = (ushort_t)bf16rn(acc[m][ti][r]);
                }
        } else if (row16 < 6) {                    // att cols 192..197
#pragma unroll
            for (int m = 0; m < 2; m++)
#pragma unroll
                for (int r = 0; r < 4; r++) {
                    int node = base + m * 16 + g * 4 + r;
                    if (row16 < 3) asrc[node * HEADS + row16] = acc[m][ti][r];
                    else           adst[node * HEADS + (row16 - 3)] = acc[m][ti][r];
                }
        }
    }
}

// ---- K2: histogram of incoming-edge counts per dst ----
__global__ void k_hist(const int* __restrict__ ei, int* __restrict__ count) {
    int i = blockIdx.x * blockDim.x + threadIdx.x;
    if (i >= ETOT) return;
    int d = (i < N_EDGES) ? ei[N_EDGES + i] : (i - N_EDGES);
    atomicAdd(&count[d], 1);
}

// ---- K3a/b/c: device-wide exclusive scan of count -> offs, cursor ----
__global__ __launch_bounds__(256) void k_scan1(
        const int* __restrict__ count, int* __restrict__ bsum) {
    __shared__ int ws[4];
    const int t = threadIdx.x, wid = t >> 6, lane = t & 63;
    int i = blockIdx.x * 256 + t;
    int v = (i < N_NODES) ? count[i] : 0;
#pragma unroll
    for (int off = 32; off; off >>= 1) v += __shfl_down(v, off);
    if (lane == 0) ws[wid] = v;
    __syncthreads();
    if (t == 0) bsum[blockIdx.x] = ws[0] + ws[1] + ws[2] + ws[3];
}

__global__ __launch_bounds__(64) void k_scan2(
        const int* __restrict__ bsum, int* __restrict__ bexc,
        int* __restrict__ offs, int nblk) {
    const int lane = threadIdx.x;
    int run = 0;
    for (int cb = 0; cb < nblk; cb += 64) {
        int i = cb + lane;
        int v = (i < nblk) ? bsum[i] : 0;
        int sc = v;
#pragma unroll
        for (int off = 1; off < 64; off <<= 1) {
            int u = __shfl_up(sc, off);
            if (lane >= off) sc += u;
        }
        if (i < nblk) bexc[i] = run + sc - v;
        run += __shfl(sc, 63);
    }
    if (lane == 0) offs[N_NODES] = run;
}

__global__ __launch_bounds__(256) void k_scan3(
        const int* __restrict__ count, const int* __restrict__ bexc,
        int* __restrict__ offs, int* __restrict__ cursor) {
    __shared__ int ws[4];
    const int t = threadIdx.x, wid = t >> 6, lane = t & 63;
    int i = blockIdx.x * 256 + t;
    int v = (i < N_NODES) ? count[i] : 0;
    int sc = v;
#pragma unroll
    for (int off = 1; off < 64; off <<= 1) {
        int u = __shfl_up(sc, off);
        if (lane >= off) sc += u;
    }
    if (lane == 63) ws[wid] = sc;
    __syncthreads();
    if (t == 0) {
        int run = 0;
#pragma unroll
        for (int j = 0; j < 4; j++) { int tmp = ws[j]; ws[j] = run; run += tmp; }
    }
    __syncthreads();
    if (i < N_NODES) {
        int e = bexc[blockIdx.x] + ws[wid] + sc - v;
        offs[i] = e; cursor[i] = e;
    }
}

// ---- K4: scatter into dst-sorted AoS, 2 edges/thread for MLP ----
__device__ __forceinline__ void scatter_one(int s, int d,
        const float* __restrict__ asrc, const float* __restrict__ adst,
        int* __restrict__ cursor, uint4* __restrict__ aos) {
    int pos = atomicAdd(&cursor[d], 1);
    float e[HEADS];
#pragma unroll
    for (int hh = 0; hh < HEADS; hh++) {
        float v = asrc[s * HEADS + hh] + adst[d * HEADS + hh];
        v = (v > 0.f) ? v : 0.2f * v;       // leaky_relu slope 0.2
        e[hh] = expf(v);                    // max-free softmax numerator
    }
    uint4 rec;
    rec.x = (unsigned)(s * (HIDDEN * 2));   // byte offset of bf16 row
    rec.y = __float_as_uint(e[0]);
    rec.z = __float_as_uint(e[1]);
    rec.w = __float_as_uint(e[2]);
    aos[pos] = rec;
}

__global__ void k_scatter(const int* __restrict__ ei,
        const float* __restrict__ asrc, const float* __restrict__ adst,
        int* __restrict__ cursor, uint4* __restrict__ aos) {
    int i = blockIdx.x * blockDim.x + threadIdx.x;
    if (i >= EHALF) return;
    int i2 = i + EHALF;
    int s0, d0, s1, d1;
    if (i < N_EDGES) { s0 = ei[i]; d0 = ei[N_EDGES + i]; }
    else             { s0 = d0 = i - N_EDGES; }
    if (i2 < N_EDGES) { s1 = ei[i2]; d1 = ei[N_EDGES + i2]; }
    else              { s1 = d1 = i2 - N_EDGES; }
    scatter_one(s0, d0, asrc, adst, cursor, aos);
    scatter_one(s1, d1, asrc, adst, cursor, aos);
}

// ---- K5: softmax-aggregate + bias + leaky_relu -> ob[n][192] bf16 ----
__global__ __launch_bounds__(192) void k_aggr(const int* __restrict__ offs,
        const uint4* __restrict__ aos, const ushort_t* __restrict__ hb,
        const float* __restrict__ bias, ushort_t* __restrict__ ob, int nbase) {
    const int n = nbase + blockIdx.x;
    const int tid = threadIdx.x;
    const int head = tid >> 6, lane = tid & 63;
    const int start = offs[n], end = offs[n + 1];
    const char* hbase = (const char*)hb + head * 128 + (lane & 7) * 16;
    const int src0 = lane >> 3;

    float acc[8];
#pragma unroll
    for (int k = 0; k < 8; k++) acc[k] = 0.f;
    float dsum = 0.f;

    for (int cb = start; cb < end; cb += 64) {
        int cnt = end - cb; if (cnt > 64) cnt = 64;
        uint4 rec = aos[cb + lane];             // slack-padded; masked below
        float myexp = 0.f; int myoff = 0;
        if (lane < cnt) {
            myexp = __uint_as_float(head == 0 ? rec.y : (head == 1 ? rec.z : rec.w));
            myoff = (int)rec.x;
        }
        dsum += myexp;
        int groups = (cnt + 7) >> 3;
#pragma unroll 2
        for (int j = 0; j < groups; j++) {
            int sl = j * 8 + src0;
            float a   = __shfl(myexp, sl);      // 0 for padded edges
            int   off = __shfl(myoff, sl);
            uint4 u = *(const uint4*)(hbase + off);
            acc[0] += a * __uint_as_float(u.x << 16);
            acc[1] += a * __uint_as_float(u.x & 0xffff0000u);
            acc[2] += a * __uint_as_float(u.y << 16);
            acc[3] += a * __uint_as_float(u.y & 0xffff0000u);
            acc[4] += a * __uint_as_float(u.z << 16);
            acc[5] += a * __uint_as_float(u.z & 0xffff0000u);
            acc[6] += a * __uint_as_float(u.w << 16);
            acc[7] += a * __uint_as_float(u.w & 0xffff0000u);
        }
    }

#pragma unroll
    for (int m = 1; m < 64; m <<= 1) dsum += __shfl_xor(dsum, m);
#pragma unroll
    for (int k = 0; k < 8; k++) {
        acc[k] += __shfl_xor(acc[k], 8);
        acc[k] += __shfl_xor(acc[k], 16);
        acc[k] += __shfl_xor(acc[k], 32);
    }

    if (lane < 8) {                 // lane owns channels head*64 + lane*8 .. +7
        const float inv = 1.f / dsum;
        const int c0 = head * HEAD_DIM + lane * 8;
        const float* bp = bias + c0;
        unsigned pk[4];
#pragma unroll
        for (int q = 0; q < 4; q++) {
            float v0 = acc[2 * q] * inv + bp[2 * q];
            float v1 = acc[2 * q + 1] * inv + bp[2 * q + 1];
            v0 = (v0 > 0.f) ? v0 : 0.01f * v0;
            v1 = (v1 > 0.f) ? v1 : 0.01f * v1;
            pk[q] = bf16rn(v0) | (bf16rn(v1) << 16);
        }
        *(uint4*)(ob + n * HIDDEN + c0) = make_uint4(pk[0], pk[1], pk[2], pk[3]);
    }
}

// ---- K5b: slab-wise max-pool over sorted batch (SLAB=64 for occupancy) ----
__global__ __launch_bounds__(192) void k_pool(
        const ushort_t* __restrict__ ob, const int* __restrict__ batch,
        unsigned* __restrict__ pooled) {
    const int t = threadIdx.x;
    const int n0 = blockIdx.x * SLAB;
    int n1 = n0 + SLAB; if (n1 > N_NODES) n1 = N_NODES;
    int curg = batch[n0];
    float m = -INFINITY;
    for (int n = n0; n < n1; n++) {
        int g = batch[n];                   // wave-uniform broadcast load
        if (g != curg) {                    // graph boundary: flush local max
            atomicMax(&pooled[curg * HIDDEN + t], f2ord(m));
            m = -INFINITY; curg = g;
        }
        m = fmaxf(m, __uint_as_float((unsigned)ob[n * HIDDEN + t] << 16));
    }
    atomicMax(&pooled[curg * HIDDEN + t], f2ord(m));
}

// ---- K6: classifier, block per graph, lane-parallel dot + reduce ----
__global__ __launch_bounds__(64) void k_cls(const unsigned* __restrict__ pooled,
        const float* __restrict__ clsW, const float* __restrict__ clsb,
        float* __restrict__ out) {
    const int g = blockIdx.x, lane = threadIdx.x;
    float s0 = 0.f, s1 = 0.f;
#pragma unroll
    for (int i = 0; i < 3; i++) {
        int f = i * 64 + lane;
        float pv = ord2f(pooled[g * HIDDEN + f]);
        s0 += pv * clsW[f * NUM_CLASSES];
        s1 += pv * clsW[f * NUM_CLASSES + 1];
    }
#pragma unroll
    for (int m = 1; m < 64; m <<= 1) {
        s0 += __shfl_xor(s0, m);
        s1 += __shfl_xor(s1, m);
    }
    if (lane == 0) {
        out[g * NUM_CLASSES]     = s0 + clsb[0];
        out[g * NUM_CLASSES + 1] = s1 + clsb[1];
    }
}

extern "C" void kernel_launch(void* const* d_in, const int* in_sizes, int n_in,
                              void* d_out, int out_size, void* d_ws, size_t ws_size,
                              hipStream_t stream) {
    const float* x       = (const float*)d_in[0];
    const int*   ei      = (const int*)d_in[1];   // [2, N_EDGES] flat
    const int*   batch   = (const int*)d_in[2];
    const float* W       = (const float*)d_in[3];
    const float* att_src = (const float*)d_in[4];
    const float* att_dst = (const float*)d_in[5];
    const float* bias    = (const float*)d_in[6];
    const float* clsW    = (const float*)d_in[7];
    const float* clsb    = (const float*)d_in[8];
    float* out = (float*)d_out;

    const int NBLK = (N_NODES + 255) / 256;   // 391 scan blocks

    char* p = (char*)d_ws;
    auto alloc = [&](size_t bytes) {
        char* r = p; p += (bytes + 255) & ~size_t(255); return r;
    };
    ushort_t* hb     = (ushort_t*)alloc(sizeof(ushort_t) * N_NODES * HIDDEN);
    ushort_t* ob     = (ushort_t*)alloc(sizeof(ushort_t) * N_NODES * HIDDEN);
    float*    asrc   = (float*)   alloc(sizeof(float) * N_NODES * HEADS);
    float*    adst   = (float*)   alloc(sizeof(float) * N_NODES * HEADS);
    int*      count  = (int*)     alloc(sizeof(int) * N_NODES);
    int*      offs   = (int*)     alloc(sizeof(int) * (N_NODES + 1));
    int*      cursor = (int*)     alloc(sizeof(int) * N_NODES);
    int*      bsum   = (int*)     alloc(sizeof(int) * NBLK);
    int*      bexc   = (int*)     alloc(sizeof(int) * NBLK);
    uint4*    aos    = (uint4*)   alloc(sizeof(uint4) * (ETOT + 64));  // +slack
    ushort_t* WT_hi  = (ushort_t*)alloc(sizeof(ushort_t) * WT_COLS * KPAD);
    ushort_t* WT_lo  = (ushort_t*)alloc(sizeof(ushort_t) * WT_COLS * KPAD);
    unsigned* pooled = (unsigned*)alloc(sizeof(unsigned) * NUM_GRAPHS * HIDDEN);

    hipMemsetAsync(count, 0, sizeof(int) * N_NODES, stream);
    hipMemsetAsync(pooled, 0, sizeof(unsigned) * NUM_GRAPHS * HIDDEN, stream);

    k_prep<<<1, 256, 0, stream>>>(W, att_src, att_dst, WT_hi, WT_lo);
    k_gemm<<<N_NODES / 32, 256, 0, stream>>>(x, WT_hi, WT_lo, hb, asrc, adst);
    k_hist<<<(ETOT + 255) / 256, 256, 0, stream>>>(ei, count);
    k_scan1<<<NBLK, 256, 0, stream>>>(count, bsum);
    k_scan2<<<1, 64, 0, stream>>>(bsum, bexc, offs, NBLK);
    k_scan3<<<NBLK, 256, 0, stream>>>(count, bexc, offs, cursor);
    k_scatter<<<(EHALF + 255) / 256, 256, 0, stream>>>(ei, asrc, adst, cursor, aos);
    k_aggr<<<N_NODES / 2, 192, 0, stream>>>(offs, aos, hb, bias, ob, 0);
    k_aggr<<<N_NODES / 2, 192, 0, stream>>>(offs, aos, hb, bias, ob, N_NODES / 2);
    k_pool<<<(N_NODES + SLAB - 1) / SLAB, 192, 0, stream>>>(ob, batch, pooled);
    k_cls<<<NUM_GRAPHS, 64, 0, stream>>>(pooled, clsW, clsb, out);
}